// Round 4
// baseline (142.345 us; speedup 1.0000x reference)
//
#include <hip/hip_runtime.h>
#include <hip/hip_bf16.h>
#include <hip/hip_cooperative_groups.h>
#include <stdint.h>
#include <math.h>

// Problem: x (B=4,L=2048,N=2048) fp32 @ W (N=2048,K=2048) ternary fp32, * scale[K],
// then per-row-of-K Poincare exp map + ball clamp. Output fp32 (8192 x 2048).
#define M_DIM 8192
#define K_DIM 2048   // reduction dim (N in reference)
#define N_DIM 2048   // output dim  (K in reference)

#define BM 256
#define BN 256
#define BK 64
#define NT (K_DIM / BK)   // 32 K-tiles

typedef __attribute__((ext_vector_type(8))) short short8;
typedef __attribute__((ext_vector_type(4))) float f32x4;
typedef __attribute__((ext_vector_type(4))) float float4v;

namespace cg = cooperative_groups;

__device__ __forceinline__ ushort f2bf(float f) {
    uint32_t u = __builtin_bit_cast(uint32_t, f);
    u = (u + 0x7fffu + ((u >> 16) & 1u)) >> 16;
    return (ushort)u;
}

// direct global->LDS DMA, 16B per lane; LDS dest = wave-uniform base + lane*16
#define GLD16(gp, lp)                                                          \
    __builtin_amdgcn_global_load_lds(                                          \
        (const __attribute__((address_space(1))) void*)(gp),                   \
        (__attribute__((address_space(3))) void*)(lp), 16, 0, 0)

// raw barrier: no vmcnt/lgkmcnt drain (unlike __syncthreads)
#define BAR()                                                                  \
    do {                                                                       \
        asm volatile("" ::: "memory");                                         \
        __builtin_amdgcn_s_barrier();                                          \
        asm volatile("" ::: "memory");                                         \
    } while (0)

#define VMCNT(n) asm volatile("s_waitcnt vmcnt(" #n ")" ::: "memory")

// ---------------- prepass 1: W (K_DIM x N_DIM fp32) -> Wt (N_DIM x K_DIM bf16) ----------
__global__ __launch_bounds__(256) void transpose_w(const float* __restrict__ W,
                                                   ushort* __restrict__ Wt) {
    __shared__ float tile[32][33];
    const int tb = blockIdx.x;
    const int kb = (tb & 63) * 32;
    const int nb = (tb >> 6) * 32;
    const int tx = threadIdx.x & 31;
    const int ty4 = (threadIdx.x >> 5) * 4;
#pragma unroll
    for (int i = 0; i < 4; i++)
        tile[ty4 + i][tx] = W[(size_t)(kb + ty4 + i) * N_DIM + nb + tx];
    __syncthreads();
#pragma unroll
    for (int i = 0; i < 4; i++)
        Wt[(size_t)(nb + ty4 + i) * K_DIM + kb + tx] = f2bf(tile[tx][ty4 + i]);
}

// ---------------- prepass 2: x fp32 -> bf16 ----------------
__global__ __launch_bounds__(256) void convert_x(const float* __restrict__ X,
                                                 ushort* __restrict__ Xb) {
    const size_t i = ((size_t)blockIdx.x * 256 + threadIdx.x) * 8;
    float4v a = *(const float4v*)&X[i];
    float4v b = *(const float4v*)&X[i + 4];
    short8 o;
    o[0] = (short)f2bf(a[0]); o[1] = (short)f2bf(a[1]);
    o[2] = (short)f2bf(a[2]); o[3] = (short)f2bf(a[3]);
    o[4] = (short)f2bf(b[0]); o[5] = (short)f2bf(b[1]);
    o[6] = (short)f2bf(b[2]); o[7] = (short)f2bf(b[3]);
    *(short8*)&Xb[i] = o;
}

// ---------------- fused GEMM + Mobius: C = mobius((Xb @ W) * scale) ----------------
// GEMM main loop identical to verified R3 (8-phase, counted vmcnt, race-free slots).
// Epilogue: deterministic per-row sumsq partials -> ws, grid.sync (cooperative),
// per-row gain g computed from full-row norm, C written ONCE as acc*scale*g.
__global__ __launch_bounds__(512, 1) void gemm_kernel(const ushort* __restrict__ Xb,
                                                      const ushort* __restrict__ Wt,
                                                      const float* __restrict__ scale,
                                                      float* __restrict__ C,
                                                      float* __restrict__ ws_part) {
    __shared__ __align__(16) ushort lds[65536];   // 128 KiB

    const int tid = threadIdx.x;
    const int w = tid >> 6;            // wave 0..7
    const int lane = tid & 63;
    const int lrow = lane & 15;
    const int khi3 = lane >> 4;        // 0..3
    const int rswz = lrow & 7;         // read-side XOR (chunk units)

    // XCD-chunked bijective swizzle (nwg=256, 8 XCDs)
    const int bid = blockIdx.x;
    const int wg = (bid & 7) * 32 + (bid >> 3);
    const int mt = wg >> 3;            // 0..31
    const int nt = wg & 7;             // 0..7
    const int row0 = mt * BM;
    const int col0 = nt * BN;

    const int wr = (w >> 2) * 128;
    const int wc = (w & 3) * 64;
    const int whalfA = w >> 2;
    const int whalfB = (w & 3) >> 1;
    const int wrB = (w & 1) * 64;

    int r_[2], c8_[2];
#pragma unroll
    for (int i = 0; i < 2; ++i) {
        const int q = (i * 8 + w) * 64 + lane;
        r_[i] = q >> 3;
        c8_[i] = (q & 7) ^ (r_[i] & 7);
    }

    auto stage2 = [&](const ushort* sb, int ldsbase) {
        GLD16(sb + (size_t)r_[0] * K_DIM + c8_[0] * 8, lds + ldsbase + (0 * 8 + w) * 512);
        GLD16(sb + (size_t)r_[1] * K_DIM + c8_[1] * 8, lds + ldsbase + (1 * 8 + w) * 512);
    };

#define RD_A(m, kk, base) (*(const short8*)&lds[(base) + ((m) * 16 + lrow) * 64 + ((((kk) * 4 + khi3) ^ rswz) * 8)])
#define RD_B(n, kk, base) (*(const short8*)&lds[(base) + (wrB + (n) * 16 + lrow) * 64 + ((((kk) * 4 + khi3) ^ rswz) * 8)])

    f32x4 acc[8][4] = {};
    short8 af[8][2], bf[4][2];

    const ushort* Asrc0 = Xb + (size_t)row0 * K_DIM;
    const ushort* Asrc1 = Xb + (size_t)(row0 + 128) * K_DIM;
    const ushort* Bsrc0 = Wt + (size_t)col0 * K_DIM;
    const ushort* Bsrc1 = Wt + (size_t)(col0 + 128) * K_DIM;

    // prologue: {A0,A1,B0,B1}[t0], {A0,A1}[t1]
    stage2(Asrc0, 0 * 8192);
    stage2(Asrc1, 1 * 8192);
    stage2(Bsrc0, 32768 + 0 * 8192);
    stage2(Bsrc1, 32768 + 1 * 8192);
    stage2(Asrc0 + BK, 2 * 8192);
    stage2(Asrc1 + BK, 3 * 8192);
    VMCNT(4);
    BAR();

#define MFMA_PHASE(m0)                                                                              \
    do {                                                                                            \
        __builtin_amdgcn_s_setprio(1);                                                              \
        _Pragma("unroll") for (int kk = 0; kk < 2; ++kk) {                                          \
            _Pragma("unroll") for (int n = 0; n < 4; ++n) {                                         \
                acc[m0][n] = __builtin_amdgcn_mfma_f32_16x16x32_bf16(af[m0][kk], bf[n][kk], acc[m0][n], 0, 0, 0);         \
                acc[m0 + 1][n] = __builtin_amdgcn_mfma_f32_16x16x32_bf16(af[m0 + 1][kk], bf[n][kk], acc[m0 + 1][n], 0, 0, 0); \
            }                                                                                       \
        }                                                                                           \
        __builtin_amdgcn_s_setprio(0);                                                              \
    } while (0)

    for (int t = 0; t < NT; ++t) {
        const int abase = ((2 * t + whalfA) & 3) * 8192;
        const int bbase = 32768 + ((2 * t + whalfB) & 3) * 8192;

        // phase 0: read B all + A m0,m1; prefetch B0[t+1]
#pragma unroll
        for (int kk = 0; kk < 2; ++kk) {
#pragma unroll
            for (int n = 0; n < 4; ++n) bf[n][kk] = RD_B(n, kk, bbase);
            af[0][kk] = RD_A(0, kk, abase);
            af[1][kk] = RD_A(1, kk, abase);
        }
        if (t + 1 < NT) stage2(Bsrc0 + (t + 1) * BK, 32768 + ((2 * (t + 1)) & 3) * 8192);
        BAR();
        MFMA_PHASE(0);
        BAR();

        // phase 1: read A m2..7; prefetch B1[t+1]
#pragma unroll
        for (int kk = 0; kk < 2; ++kk) {
#pragma unroll
            for (int m = 2; m < 8; ++m) af[m][kk] = RD_A(m, kk, abase);
        }
        if (t + 1 < NT) stage2(Bsrc1 + (t + 1) * BK, 32768 + ((2 * (t + 1) + 1) & 3) * 8192);
        BAR();
        MFMA_PHASE(2);
        BAR();
        // tile t's LDS reads all complete here -> its slots are reusable

        // phase 2: prefetch A0[t+2]
        if (t + 2 < NT) stage2(Asrc0 + (t + 2) * BK, ((2 * (t + 2)) & 3) * 8192);
        BAR();
        MFMA_PHASE(4);
        BAR();

        // phase 3: prefetch A1[t+2]; counted vmcnt
        if (t + 2 < NT) stage2(Asrc1 + (t + 2) * BK, ((2 * (t + 2) + 1) & 3) * 8192);
        if (t < NT - 2) { VMCNT(4); } else { VMCNT(0); }
        BAR();
        MFMA_PHASE(6);
        BAR();
    }

    // ================= fused Mobius epilogue =================
    __syncthreads();                       // LDS now reusable for reductions
    float* part = (float*)lds;             // [4][256] per-colgroup row partials
    float* gl = part + 1024;               // [256] per-row gain
    const int h = lane >> 4;
    const int ccol = col0 + wc + lrow;
    float scv[4];
#pragma unroll
    for (int n = 0; n < 4; ++n) scv[n] = scale[ccol + n * 16];

    // per-(m,j): sumsq over this wave's 64 cols (4 n-frags x 16 lanes)
#pragma unroll
    for (int m = 0; m < 8; ++m) {
#pragma unroll
        for (int j = 0; j < 4; ++j) {
            float v = 0.f;
#pragma unroll
            for (int n = 0; n < 4; ++n) {
                const float t0 = acc[m][n][j] * scv[n];
                v += t0 * t0;
            }
            v += __shfl_xor(v, 1);
            v += __shfl_xor(v, 2);
            v += __shfl_xor(v, 4);
            v += __shfl_xor(v, 8);
            if ((lane & 15) == 0) part[(w & 3) * 256 + wr + m * 16 + h * 4 + j] = v;
        }
    }
    __syncthreads();
    // block partial per row -> ws (deterministic: every slot written exactly once)
    if (tid < 256) {
        const float s = part[tid] + part[256 + tid] + part[512 + tid] + part[768 + tid];
        ws_part[(size_t)(row0 + tid) * 8 + nt] = s;
    }
    cg::this_grid().sync();
    // full-row norm -> Mobius gain
    if (tid < 256) {
        const float* pp = ws_part + (size_t)(row0 + tid) * 8;
        float tot = 0.f;
#pragma unroll
        for (int i = 0; i < 8; ++i) tot += pp[i];
        const float vn = fmaxf(sqrtf(tot), 1e-7f);
        const float tf = tanhf(vn) / (vn + 1e-7f);
        const float on = fmaxf(tf * vn, 1e-7f);
        gl[tid] = tf * fminf(0.99f / on, 1.0f);
    }
    __syncthreads();
    // single C write: acc * scale[col] * g[row]
    const int crow0 = row0 + wr + h * 4;
#pragma unroll
    for (int n = 0; n < 4; ++n) {
#pragma unroll
        for (int m = 0; m < 8; ++m) {
#pragma unroll
            for (int j = 0; j < 4; ++j) {
                const float g = gl[wr + m * 16 + h * 4 + j];
                C[(size_t)(crow0 + m * 16 + j) * N_DIM + ccol + n * 16] = acc[m][n][j] * scv[n] * g;
            }
        }
    }
#undef RD_A
#undef RD_B
#undef MFMA_PHASE
}

extern "C" void kernel_launch(void* const* d_in, const int* in_sizes, int n_in,
                              void* d_out, int out_size, void* d_ws, size_t ws_size,
                              hipStream_t stream) {
    const float* x = (const float*)d_in[0];
    const float* w = (const float*)d_in[1];
    const float* scale = (const float*)d_in[2];
    float* out = (float*)d_out;

    ushort* Wt = (ushort*)d_ws;                                         // 8 MB
    ushort* Xb = (ushort*)((char*)d_ws + (size_t)8 * 1024 * 1024);      // 32 MB
    float* wsp = (float*)((char*)d_ws + (size_t)40 * 1024 * 1024);      // 256 KB row partials

    transpose_w<<<dim3(64 * 64), dim3(256), 0, stream>>>(w, Wt);
    convert_x<<<dim3((M_DIM * K_DIM) / (8 * 256)), dim3(256), 0, stream>>>(x, Xb);

    const ushort* XbC = Xb;
    const ushort* WtC = Wt;
    void* args[] = {(void*)&XbC, (void*)&WtC, (void*)&scale, (void*)&out, (void*)&wsp};
    hipLaunchCooperativeKernel((const void*)gemm_kernel, dim3((M_DIM / BM) * (N_DIM / BN)),
                               dim3(512), args, 0, stream);
}

// Round 6
// 108.479 us; speedup vs baseline: 1.3122x; 1.3122x over previous
//
#include <hip/hip_runtime.h>
#include <hip/hip_bf16.h>
#include <stdint.h>
#include <math.h>

// Problem: x (B=4,L=2048,N=2048) fp32 @ W (N=2048,K=2048) ternary fp32, * scale[K],
// then per-row-of-K Poincare exp map + ball clamp. Output fp32 (8192 x 2048).
#define M_DIM 8192
#define K_DIM 2048   // reduction dim (N in reference)
#define N_DIM 2048   // output dim  (K in reference)

#define BM 256
#define BN 256
#define BK 64
#define NT (K_DIM / BK)   // 32 K-tiles

typedef __attribute__((ext_vector_type(8))) short short8;
typedef __attribute__((ext_vector_type(4))) float f32x4;
typedef __attribute__((ext_vector_type(4))) float float4v;

__device__ __forceinline__ ushort f2bf(float f) {
    uint32_t u = __builtin_bit_cast(uint32_t, f);
    u = (u + 0x7fffu + ((u >> 16) & 1u)) >> 16;
    return (ushort)u;
}

// direct global->LDS DMA, 16B per lane; LDS dest = wave-uniform base + lane*16
#define GLD16(gp, lp)                                                          \
    __builtin_amdgcn_global_load_lds(                                          \
        (const __attribute__((address_space(1))) void*)(gp),                   \
        (__attribute__((address_space(3))) void*)(lp), 16, 0, 0)

// raw barrier: no vmcnt/lgkmcnt drain (unlike __syncthreads)
#define BAR()                                                                  \
    do {                                                                       \
        asm volatile("" ::: "memory");                                         \
        __builtin_amdgcn_s_barrier();                                          \
        asm volatile("" ::: "memory");                                         \
    } while (0)

#define VMCNT(n) asm volatile("s_waitcnt vmcnt(" #n ")" ::: "memory")

// ---------------- prepass 1: W (K_DIM x N_DIM fp32) -> Wt (N_DIM x K_DIM bf16) ----------
__global__ __launch_bounds__(256) void transpose_w(const float* __restrict__ W,
                                                   ushort* __restrict__ Wt) {
    __shared__ float tile[32][33];
    const int tb = blockIdx.x;
    const int kb = (tb & 63) * 32;
    const int nb = (tb >> 6) * 32;
    const int tx = threadIdx.x & 31;
    const int ty4 = (threadIdx.x >> 5) * 4;
#pragma unroll
    for (int i = 0; i < 4; i++)
        tile[ty4 + i][tx] = W[(size_t)(kb + ty4 + i) * N_DIM + nb + tx];
    __syncthreads();
#pragma unroll
    for (int i = 0; i < 4; i++)
        Wt[(size_t)(nb + ty4 + i) * K_DIM + kb + tx] = f2bf(tile[tx][ty4 + i]);
}

// ---------------- prepass 2: x fp32 -> bf16 ----------------
__global__ __launch_bounds__(256) void convert_x(const float* __restrict__ X,
                                                 ushort* __restrict__ Xb) {
    const size_t i = ((size_t)blockIdx.x * 256 + threadIdx.x) * 8;
    float4v a = *(const float4v*)&X[i];
    float4v b = *(const float4v*)&X[i + 4];
    short8 o;
    o[0] = (short)f2bf(a[0]); o[1] = (short)f2bf(a[1]);
    o[2] = (short)f2bf(a[2]); o[3] = (short)f2bf(a[3]);
    o[4] = (short)f2bf(b[0]); o[5] = (short)f2bf(b[1]);
    o[6] = (short)f2bf(b[2]); o[7] = (short)f2bf(b[3]);
    *(short8*)&Xb[i] = o;
}

// ---------------- GEMM: C = (Xb @ W) * scale ----------------
// 256x256 tile, BK=64, 8 waves (2M x 4N), per-wave C = 128x64.
// 4 phases per K-tile, kk-split quadrants -> reads spread 8/4/8/4:
//   p0: read B(kk0)+A m0-3(kk0); stage A0[t+1], B0[t+1]; MFMA m0-3 kk0
//   p1: read A m4-7(kk0);        stage A1[t+1], B1[t+1]; MFMA m4-7 kk0
//   p2: read B(kk1)+A m0-3(kk1);                         MFMA m0-3 kk1
//   p3: read A m4-7(kk1); VMCNT(0); BAR;                 MFMA m4-7 kk1
// Slot safety (strict barrier ordering, no timing windows):
//   A[t+1]@p0/p1 -> A[t-1] slots, whose last reads (af3) completed before
//   t-1's final barrier (lgkmcnt before p3 MFMA). B[t+1]@p0/p1 -> B[t-1]
//   slots, last read (bf2) completed at t-1 p2. Both strictly precede t p0.
// Drain correctness (the R5 bug, fixed): each wave's VMCNT(0) executes BEFORE
// the p3 pre-MFMA barrier, so passing that barrier certifies ALL waves'
// tile-t+1 staging has landed; t+1's reads start after the next barrier.
// Cover: loads issued p0/p1, drained p3 (~2-3 phases > HBM latency) -> ~0 stall.
template <bool BF16OUT>
__global__ __launch_bounds__(512, 1) void gemm_kernel(const ushort* __restrict__ Xb,
                                                      const ushort* __restrict__ Wt,
                                                      const float* __restrict__ scale,
                                                      float* __restrict__ Cf,
                                                      ushort* __restrict__ Cb) {
    __shared__ __align__(16) ushort lds[65536];   // 128 KiB: A [0,32768), B [32768,65536)

    const int tid = threadIdx.x;
    const int w = tid >> 6;            // wave 0..7
    const int lane = tid & 63;
    const int lrow = lane & 15;
    const int khi3 = lane >> 4;        // 0..3
    const int rswz = lrow & 7;         // read-side XOR (chunk units)

    // XCD-chunked bijective swizzle (nwg=256, 8 XCDs)
    const int bid = blockIdx.x;
    const int wg = (bid & 7) * 32 + (bid >> 3);
    const int mt = wg >> 3;            // 0..31
    const int nt = wg & 7;             // 0..7
    const int row0 = mt * BM;
    const int col0 = nt * BN;

    const int wr = (w >> 2) * 128;
    const int wc = (w & 3) * 64;
    const int whalfA = w >> 2;
    const int whalfB = (w & 3) >> 1;
    const int wrB = (w & 1) * 64;

    int r_[2], c8_[2];
#pragma unroll
    for (int i = 0; i < 2; ++i) {
        const int q = (i * 8 + w) * 64 + lane;
        r_[i] = q >> 3;
        c8_[i] = (q & 7) ^ (r_[i] & 7);
    }

    auto stage2 = [&](const ushort* sb, int ldsbase) {
        GLD16(sb + (size_t)r_[0] * K_DIM + c8_[0] * 8, lds + ldsbase + (0 * 8 + w) * 512);
        GLD16(sb + (size_t)r_[1] * K_DIM + c8_[1] * 8, lds + ldsbase + (1 * 8 + w) * 512);
    };

#define RD_A(m, kk, base) (*(const short8*)&lds[(base) + ((m) * 16 + lrow) * 64 + ((((kk) * 4 + khi3) ^ rswz) * 8)])
#define RD_B(n, kk, base) (*(const short8*)&lds[(base) + (wrB + (n) * 16 + lrow) * 64 + ((((kk) * 4 + khi3) ^ rswz) * 8)])

    f32x4 acc[8][4] = {};

    const ushort* Asrc0 = Xb + (size_t)row0 * K_DIM;
    const ushort* Asrc1 = Xb + (size_t)(row0 + 128) * K_DIM;
    const ushort* Bsrc0 = Wt + (size_t)col0 * K_DIM;
    const ushort* Bsrc1 = Wt + (size_t)(col0 + 128) * K_DIM;

    // prologue: stage tile 0, drain, barrier
    stage2(Asrc0, 0 * 8192);
    stage2(Asrc1, 1 * 8192);
    stage2(Bsrc0, 32768 + 0 * 8192);
    stage2(Bsrc1, 32768 + 1 * 8192);
    VMCNT(0);
    BAR();

    for (int t = 0; t < NT; ++t) {
        const int abase = ((2 * t + whalfA) & 3) * 8192;
        const int bbase = 32768 + ((2 * t + whalfB) & 3) * 8192;
        const bool pf = (t + 1 < NT);
        const int aslot0 = ((2 * (t + 1)) & 3) * 8192;
        const int aslot1 = ((2 * (t + 1) + 1) & 3) * 8192;
        const int bslot0 = 32768 + ((2 * (t + 1)) & 3) * 8192;
        const int bslot1 = 32768 + ((2 * (t + 1) + 1) & 3) * 8192;

        short8 af0[4], af1[4], af2[4], af3[4], bf0[4], bf2[4];

        // ---- phase 0: reads (8) + stage A0,B0[t+1] ----
#pragma unroll
        for (int n = 0; n < 4; ++n) bf0[n] = RD_B(n, 0, bbase);
#pragma unroll
        for (int m = 0; m < 4; ++m) af0[m] = RD_A(m, 0, abase);
        if (pf) {
            stage2(Asrc0 + (t + 1) * BK, aslot0);
            stage2(Bsrc0 + (t + 1) * BK, bslot0);
        }
        BAR();
        __builtin_amdgcn_s_setprio(1);
#pragma unroll
        for (int m = 0; m < 4; ++m)
#pragma unroll
            for (int n = 0; n < 4; ++n)
                acc[m][n] = __builtin_amdgcn_mfma_f32_16x16x32_bf16(af0[m], bf0[n], acc[m][n], 0, 0, 0);
        __builtin_amdgcn_s_setprio(0);
        BAR();

        // ---- phase 1: reads (4) + stage A1,B1[t+1] ----
#pragma unroll
        for (int m = 0; m < 4; ++m) af1[m] = RD_A(4 + m, 0, abase);
        if (pf) {
            stage2(Asrc1 + (t + 1) * BK, aslot1);
            stage2(Bsrc1 + (t + 1) * BK, bslot1);
        }
        BAR();
        __builtin_amdgcn_s_setprio(1);
#pragma unroll
        for (int m = 0; m < 4; ++m)
#pragma unroll
            for (int n = 0; n < 4; ++n)
                acc[4 + m][n] = __builtin_amdgcn_mfma_f32_16x16x32_bf16(af1[m], bf0[n], acc[4 + m][n], 0, 0, 0);
        __builtin_amdgcn_s_setprio(0);
        BAR();

        // ---- phase 2: reads (8) ----
#pragma unroll
        for (int n = 0; n < 4; ++n) bf2[n] = RD_B(n, 1, bbase);
#pragma unroll
        for (int m = 0; m < 4; ++m) af2[m] = RD_A(m, 1, abase);
        BAR();
        __builtin_amdgcn_s_setprio(1);
#pragma unroll
        for (int m = 0; m < 4; ++m)
#pragma unroll
            for (int n = 0; n < 4; ++n)
                acc[m][n] = __builtin_amdgcn_mfma_f32_16x16x32_bf16(af2[m], bf2[n], acc[m][n], 0, 0, 0);
        __builtin_amdgcn_s_setprio(0);
        BAR();

        // ---- phase 3: reads (4); drain BEFORE barrier (correctness-critical) ----
#pragma unroll
        for (int m = 0; m < 4; ++m) af3[m] = RD_A(4 + m, 1, abase);
        VMCNT(0);   // this wave's tile-t+1 staging landed; barrier certifies all waves
        BAR();
        __builtin_amdgcn_s_setprio(1);
#pragma unroll
        for (int m = 0; m < 4; ++m)
#pragma unroll
            for (int n = 0; n < 4; ++n)
                acc[4 + m][n] = __builtin_amdgcn_mfma_f32_16x16x32_bf16(af3[m], bf2[n], acc[4 + m][n], 0, 0, 0);
        __builtin_amdgcn_s_setprio(0);
        BAR();
    }

    // ---- epilogue: apply per-column scale, write ----
    const int crow0 = row0 + wr + (lane >> 4) * 4;
    const int ccol = col0 + wc + lrow;
#pragma unroll
    for (int n = 0; n < 4; ++n) {
        const float sc = scale[ccol + n * 16];
#pragma unroll
        for (int m = 0; m < 8; ++m) {
#pragma unroll
            for (int j = 0; j < 4; ++j) {
                const float v = acc[m][n][j] * sc;
                const size_t idx = (size_t)(crow0 + m * 16 + j) * N_DIM + ccol + n * 16;
                if constexpr (BF16OUT) Cb[idx] = f2bf(v);
                else                   Cf[idx] = v;
            }
        }
    }
#undef RD_A
#undef RD_B
}

// ---------------- Mobius epilogue, bf16 input variant ----------------
__global__ __launch_bounds__(256) void mobius_bf16(const ushort* __restrict__ Cb,
                                                   float* __restrict__ out) {
    const ushort* p = Cb + (size_t)blockIdx.x * N_DIM;
    float* q = out + (size_t)blockIdx.x * N_DIM;
    const int t = threadIdx.x;
    short8 v = *(const short8*)&p[t * 8];
    float f[8];
#pragma unroll
    for (int j = 0; j < 8; ++j) {
        const uint32_t u = ((uint32_t)(uint16_t)v[j]) << 16;
        f[j] = __builtin_bit_cast(float, u);
    }
    float ss = 0.f;
#pragma unroll
    for (int j = 0; j < 8; ++j) ss += f[j] * f[j];
#pragma unroll
    for (int off = 1; off < 64; off <<= 1) ss += __shfl_xor(ss, off);
    __shared__ float wsum[4];
    if ((t & 63) == 0) wsum[t >> 6] = ss;
    __syncthreads();
    const float tot = wsum[0] + wsum[1] + wsum[2] + wsum[3];
    const float vn = fmaxf(sqrtf(tot), 1e-7f);
    const float tf = tanhf(vn) / (vn + 1e-7f);
    const float on = fmaxf(tf * vn, 1e-7f);
    const float g = tf * fminf(0.99f / on, 1.0f);
    float4v o0, o1;
#pragma unroll
    for (int j = 0; j < 4; ++j) { o0[j] = f[j] * g; o1[j] = f[4 + j] * g; }
    *(float4v*)&q[t * 8] = o0;
    *(float4v*)&q[t * 8 + 4] = o1;
}

// ---------------- Mobius epilogue, fp32 in-place variant (fallback) ----------------
__global__ __launch_bounds__(256) void mobius_rows(float* __restrict__ C) {
    float* p = C + (size_t)blockIdx.x * N_DIM;
    const int t = threadIdx.x;
    float4v a = *(const float4v*)&p[t * 8];
    float4v b = *(const float4v*)&p[t * 8 + 4];
    float ss = a[0]*a[0] + a[1]*a[1] + a[2]*a[2] + a[3]*a[3]
             + b[0]*b[0] + b[1]*b[1] + b[2]*b[2] + b[3]*b[3];
#pragma unroll
    for (int off = 1; off < 64; off <<= 1) ss += __shfl_xor(ss, off);
    __shared__ float wsum[4];
    if ((t & 63) == 0) wsum[t >> 6] = ss;
    __syncthreads();
    const float tot = wsum[0] + wsum[1] + wsum[2] + wsum[3];
    const float vn = fmaxf(sqrtf(tot), 1e-7f);
    const float tf = tanhf(vn) / (vn + 1e-7f);
    const float on = fmaxf(tf * vn, 1e-7f);
    const float g = tf * fminf(0.99f / on, 1.0f);
#pragma unroll
    for (int j = 0; j < 4; j++) { a[j] *= g; b[j] *= g; }
    *(float4v*)&p[t * 8] = a;
    *(float4v*)&p[t * 8 + 4] = b;
}

extern "C" void kernel_launch(void* const* d_in, const int* in_sizes, int n_in,
                              void* d_out, int out_size, void* d_ws, size_t ws_size,
                              hipStream_t stream) {
    const float* x = (const float*)d_in[0];
    const float* w = (const float*)d_in[1];
    const float* scale = (const float*)d_in[2];
    float* out = (float*)d_out;

    // ws layout (exact): Wt @0 (8388608 B), Xb @8388608 (33554432 B), Cb @41943040 (33554432 B)
    ushort* Wt = (ushort*)d_ws;
    ushort* Xb = (ushort*)((char*)d_ws + 8388608);
    ushort* Cb = (ushort*)((char*)d_ws + 41943040);
    const bool use_bf16c = (ws_size >= 75497472);   // constant per session -> deterministic

    transpose_w<<<dim3(64 * 64), dim3(256), 0, stream>>>(w, Wt);
    convert_x<<<dim3((M_DIM * K_DIM) / (8 * 256)), dim3(256), 0, stream>>>(x, Xb);

    if (use_bf16c) {
        gemm_kernel<true><<<dim3((M_DIM / BM) * (N_DIM / BN)), dim3(512), 0, stream>>>(
            Xb, Wt, scale, nullptr, Cb);
        mobius_bf16<<<dim3(M_DIM), dim3(256), 0, stream>>>(Cb, out);
    } else {
        gemm_kernel<false><<<dim3((M_DIM / BM) * (N_DIM / BN)), dim3(512), 0, stream>>>(
            Xb, Wt, scale, out, nullptr);
        mobius_rows<<<dim3(M_DIM), dim3(256), 0, stream>>>(out);
    }
}